// Round 15
// baseline (74.390 us; speedup 1.0000x reference)
//
#include <hip/hip_runtime.h>
#include <hip/hip_bf16.h>

typedef unsigned short u16;
typedef __attribute__((ext_vector_type(8))) short bf16x8;
typedef __attribute__((ext_vector_type(4))) float f32x4;
typedef __attribute__((ext_vector_type(16))) float f32x16;

#define S_LEN 2048
#define NH 16

__device__ __forceinline__ u16 f2bf(float x) {
  union { float f; unsigned u; } v; v.f = x;
  unsigned r = v.u + 0x7fffu + ((v.u >> 16) & 1u);
  return (u16)(r >> 16);
}

__device__ __forceinline__ unsigned cvtpk_bf16(float lo, float hi) {
  unsigned w;
  asm("v_cvt_pk_bf16_f32 %0, %1, %2" : "=v"(w) : "v"(lo), "v"(hi));
  return w;
}

// swap a's hi 32 lanes with b's lo 32 lanes (both updated)
__device__ __forceinline__ void plswap(unsigned& a, unsigned& b) {
  asm volatile("v_permlane32_swap_b32 %0, %1" : "+v"(a), "+v"(b));
}

__device__ __forceinline__ float fexp2(float x) {
#if __has_builtin(__builtin_amdgcn_exp2f)
  return __builtin_amdgcn_exp2f(x);
#else
  float y;
  asm volatile("v_exp_f32 %0, %1\n\ts_nop 0" : "=v"(y) : "v"(x));
  return y;
#endif
}

__device__ __forceinline__ void async16(const void* g, void* l) {
  __builtin_amdgcn_global_load_lds(
      (const __attribute__((address_space(1))) unsigned int*)g,
      (__attribute__((address_space(3))) unsigned int*)l, 16, 0, 0);
}

__device__ __forceinline__ f32x4 mfma16(bf16x8 a, bf16x8 b, f32x4 c) {
  return __builtin_amdgcn_mfma_f32_16x16x32_bf16(a, b, c, 0, 0, 0);
}
__device__ __forceinline__ f32x16 mfma32(bf16x8 a, bf16x8 b, f32x16 c) {
  return __builtin_amdgcn_mfma_f32_32x32x16_bf16(a, b, c, 0, 0, 0);
}

// scale folded into Wq/bq: 1/sqrt(64) * log2(e) so QK^T output is the exp2 arg
#define QSCALE (0.125f * 1.44269504089f)

// ---------------------------------------------------------------------------
// K1: convert/pack (region-dispatched by blockIdx.x). Unchanged (round 12).
// ---------------------------------------------------------------------------
__global__ __launch_bounds__(256) void convert_kernel(
    const float* __restrict__ emb, const float* __restrict__ Wq,
    const float* __restrict__ Wk, const float* __restrict__ Wv,
    const float* __restrict__ bq, const float* __restrict__ bk,
    const float* __restrict__ bv, const float* __restrict__ Wo,
    u16* __restrict__ emb_bf, u16* __restrict__ wqkv_t,
    u16* __restrict__ wo_t, float* __restrict__ bqkv) {
  __shared__ float lds[64][65];
  const int b = blockIdx.x, tid = threadIdx.x;
  if (b < 2048) {
    int i = b * 1024 + tid * 4;
    float4 v = *(const float4*)(emb + i);
    ushort4 o = {f2bf(v.x), f2bf(v.y), f2bf(v.z), f2bf(v.w)};
    *(ushort4*)(emb_bf + i) = o;
    return;
  }
  if (b < 2816) {
    int tt = b - 2048;
    int kind = tt >> 8;
    int rem = tt & 255;
    int h = rem >> 4, k0 = (rem & 15) << 6;
    const float* W = (kind == 0) ? Wq : ((kind == 1) ? Wk : Wv);
    const float* src = W + ((size_t)h * 1024 + k0) * 64;
#pragma unroll
    for (int rr = 0; rr < 4; ++rr) {
      int k = rr * 16 + (tid >> 4);
      int d4 = (tid & 15) << 2;
      float4 v = *(const float4*)(src + (size_t)k * 64 + d4);
      lds[k][d4] = v.x; lds[k][d4 + 1] = v.y;
      lds[k][d4 + 2] = v.z; lds[k][d4 + 3] = v.w;
    }
    __syncthreads();
    float scale = (kind == 0) ? QSCALE : 1.f;
#pragma unroll
    for (int p = 0; p < 2; ++p) {
      int d = p * 32 + (tid >> 3);
      int kb = (tid & 7) << 3;
      bf16x8 o;
#pragma unroll
      for (int j = 0; j < 8; ++j) o[j] = (short)f2bf(lds[kb + j][d] * scale);
      *(bf16x8*)(wqkv_t + (size_t)(kind * 1024 + h * 64 + d) * 1024 + k0 + kb) = o;
    }
    return;
  }
  if (b < 3072) {
    int tt = b - 2816;
    int k0 = (tt >> 4) << 6, n0 = (tt & 15) << 6;
#pragma unroll
    for (int rr = 0; rr < 4; ++rr) {
      int k = rr * 16 + (tid >> 4);
      int n4 = (tid & 15) << 2;
      float4 v = *(const float4*)(Wo + (size_t)(k0 + k) * 1024 + n0 + n4);
      lds[k][n4] = v.x; lds[k][n4 + 1] = v.y;
      lds[k][n4 + 2] = v.z; lds[k][n4 + 3] = v.w;
    }
    __syncthreads();
#pragma unroll
    for (int p = 0; p < 2; ++p) {
      int nrel = p * 32 + (tid >> 3);
      int kb = (tid & 7) << 3;
      bf16x8 o;
#pragma unroll
      for (int j = 0; j < 8; ++j) o[j] = (short)f2bf(lds[kb + j][nrel]);
      *(bf16x8*)(wo_t + (size_t)(n0 + nrel) * 1024 + k0 + kb) = o;
    }
    return;
  }
  for (int i = tid; i < 3072; i += 256) {
    int kind = i >> 10, hd = i & 1023;
    const float* bb = (kind == 0) ? bq : ((kind == 1) ? bk : bv);
    float v = bb[hd];
    bqkv[i] = (kind == 0) ? v * QSCALE : v;
  }
}

// ---------------------------------------------------------------------------
// GEMM (round-6 proven form: 2-buf, vmcnt(0)+syncthreads). Unchanged.
// SPLIT (GEMM1, BN=64 tiles): Q -> qbuf[2048][1024]; K -> kpack frag tiles;
// V -> vpack frag tiles (lane-linear 1KB tiles).
// ---------------------------------------------------------------------------
template <int WM, int WN, int FM, int FN, int BK, bool OUT_BF16, bool SPLIT>
__global__ __launch_bounds__(WM * WN * 64) void gemm_kernel(
    const u16* __restrict__ A, const u16* __restrict__ BT,
    const float* __restrict__ bias, void* __restrict__ Cout,
    u16* __restrict__ kp, u16* __restrict__ vp, int M, int N, int K) {
  constexpr int BM = WM * FM * 16, BN = WN * FN * 16, T = WM * WN * 64;
  constexpr int RB = BK * 2;
  __shared__ u16 lds[2][(BM + BN) * BK];
  const int tid = threadIdx.x;
  const int lane = tid & 63, wave = tid >> 6;
  const int wr = wave / WN, wc = wave % WN;
  const int m0 = blockIdx.x * BM, n0 = blockIdx.y * BN;
  const int r = lane & 15, g = lane >> 4;
  const f32x4 fzero = {0.f, 0.f, 0.f, 0.f};
  f32x4 acc[FM][FN];
#pragma unroll
  for (int i = 0; i < FM; ++i)
#pragma unroll
    for (int j = 0; j < FN; ++j) acc[i][j] = fzero;

  constexpr int LA = (BM * RB) / (T * 16);
  constexpr int LB = (BN * RB) / (T * 16);

  auto stage = [&](int kt, int buf) {
    int k0 = kt * BK;
#pragma unroll
    for (int i = 0; i < LA; ++i) {
      int flat = i * T * 16 + tid * 16;
      int row = flat / RB, colb = flat % RB;
      async16((const char*)A + ((size_t)(m0 + row) * K + k0) * 2 + colb,
              (char*)lds[buf] + i * T * 16 + wave * 1024);
    }
#pragma unroll
    for (int i = 0; i < LB; ++i) {
      int flat = i * T * 16 + tid * 16;
      int row = flat / RB, colb = flat % RB;
      async16((const char*)BT + ((size_t)(n0 + row) * K + k0) * 2 + colb,
              (char*)lds[buf] + BM * RB + i * T * 16 + wave * 1024);
    }
  };

  stage(0, 0);
  asm volatile("s_waitcnt vmcnt(0)" ::: "memory");
  __syncthreads();

  const int NT = K / BK;
  for (int kt = 0; kt < NT; ++kt) {
    int cur = kt & 1;
    if (kt + 1 < NT) stage(kt + 1, cur ^ 1);
    const u16* Al = lds[cur];
    const u16* Bl = Al + BM * BK;
#pragma unroll
    for (int kk = 0; kk < BK / 32; ++kk) {
      bf16x8 af[FM], bfr[FN];
#pragma unroll
      for (int i = 0; i < FM; ++i)
        af[i] = *(const bf16x8*)&Al[(wr * FM * 16 + i * 16 + r) * BK + kk * 32 + g * 8];
#pragma unroll
      for (int j = 0; j < FN; ++j)
        bfr[j] = *(const bf16x8*)&Bl[(wc * FN * 16 + j * 16 + r) * BK + kk * 32 + g * 8];
#pragma unroll
      for (int i = 0; i < FM; ++i)
#pragma unroll
        for (int j = 0; j < FN; ++j)
          acc[i][j] = mfma16(af[i], bfr[j], acc[i][j]);
    }
    asm volatile("s_waitcnt vmcnt(0)" ::: "memory");
    __syncthreads();
  }

  if constexpr (SPLIT) {
    if (n0 >= 2048) {  // V head -> vpack frag tiles
      int h = (n0 - 2048) >> 6;
      u16* base = vp + (size_t)h * 131072;
#pragma unroll
      for (int i = 0; i < FM; ++i)
#pragma unroll
        for (int j = 0; j < FN; ++j) {
          int d = wc * FN * 16 + j * 16 + r;
          int t0v = m0 + wr * FM * 16 + i * 16 + g * 4;
          float bval = bias[n0 + d];
          int off = (t0v >> 6) * 4096 + ((((t0v >> 4) & 3) * 2 + (d >> 5))) * 512 +
                    ((d & 31) * 2 + ((t0v >> 3) & 1)) * 8 + (t0v & 7);
          ushort4 o = {f2bf(acc[i][j][0] + bval), f2bf(acc[i][j][1] + bval),
                       f2bf(acc[i][j][2] + bval), f2bf(acc[i][j][3] + bval)};
          *(ushort4*)(base + off) = o;
        }
      return;
    }
    if (n0 >= 1024) {  // K head -> kpack frag tiles
      int h = (n0 - 1024) >> 6;
      u16* base = kp + (size_t)h * 131072;
#pragma unroll
      for (int i = 0; i < FM; ++i)
#pragma unroll
        for (int j = 0; j < FN; ++j) {
          int d = wc * FN * 16 + j * 16 + r;
          float bval = bias[n0 + d];
#pragma unroll
          for (int e = 0; e < 4; ++e) {
            int t = m0 + wr * FM * 16 + i * 16 + g * 4 + e;
            int off = (t >> 5) * 2048 + (d >> 4) * 512 +
                      ((t & 31) * 2 + ((d >> 3) & 1)) * 8 + (d & 7);
            base[off] = f2bf(acc[i][j][e] + bval);
          }
        }
      return;
    }
    // Q -> qbuf[2048][1024]
#pragma unroll
    for (int i = 0; i < FM; ++i)
#pragma unroll
      for (int j = 0; j < FN; ++j)
#pragma unroll
        for (int e = 0; e < 4; ++e) {
          int row = m0 + wr * FM * 16 + i * 16 + g * 4 + e;
          int col = n0 + wc * FN * 16 + j * 16 + r;
          ((u16*)Cout)[(size_t)row * 1024 + col] = f2bf(acc[i][j][e] + bias[col]);
        }
    return;
  }

#pragma unroll
  for (int i = 0; i < FM; ++i)
#pragma unroll
    for (int j = 0; j < FN; ++j)
#pragma unroll
      for (int e = 0; e < 4; ++e) {
        int row = m0 + wr * FM * 16 + i * 16 + g * 4 + e;
        int col = n0 + wc * FN * 16 + j * 16 + r;
        float v = acc[i][j][e] + bias[col];
        if constexpr (OUT_BF16)
          ((u16*)Cout)[(size_t)row * N + col] = f2bf(v);
        else
          ((float*)Cout)[(size_t)row * N + col] = v;
      }
}

// ---------------------------------------------------------------------------
// K4: register-resident flash attention, 32-KEY STEPS (half of the verified
// round-8 step; same index algebra). Per-step footprint K 4KB + V 4KB fits
// L1 (32KB) across all 4 waves -> the block's waves draft off the leader's
// L2 misses without barriers. NO LDS, NO barriers.
// 256 blocks x 4 waves; wave = 32 q-rows x 2048 keys, one head.
// ---------------------------------------------------------------------------
__global__ __launch_bounds__(256, 1) void attn_kernel(const u16* __restrict__ qbuf,
                                                      const u16* __restrict__ kp,
                                                      const u16* __restrict__ vp,
                                                      u16* __restrict__ concat) {
  const int tid = threadIdx.x, lane = tid & 63, wave = tid >> 6;
  // XCD swizzle: 32 consecutive jobs (2 heads) per XCD
  const int swz = (blockIdx.x & 7) * 32 + (blockIdx.x >> 3);
  const int h = swz >> 4, qg = swz & 15;
  const int q0w = qg * 128 + wave * 32;
  const int l31 = lane & 31, hi5 = lane >> 5;
  const char* kb = (const char*)kp + (size_t)h * 262144;
  const char* vb = (const char*)vp + (size_t)h * 262144;
  const int loff = (l31 * 2 + hi5) * 16;  // lane-linear frag offset (bytes)

  // Q fragments (B-operand): lane holds Q[q=l31][ds*16 + hi5*8 + j]
  bf16x8 qf[4];
#pragma unroll
  for (int ds = 0; ds < 4; ++ds)
    qf[ds] = *(const bf16x8*)&qbuf[(size_t)(q0w + l31) * 1024 + h * 64 + ds * 16 + hi5 * 8];

  f32x16 acc0 = {}, acc1 = {};
  float rs = 0.f;

  bf16x8 kA[4], kB[4];
#pragma unroll
  for (int i = 0; i < 4; ++i) kA[i] = *(const bf16x8*)(kb + i * 1024 + loff);

  auto stepf = [&](int t, bf16x8(&kc)[4], bf16x8(&kn)[4]) {
    // V frags for this 32-key step (contiguous 4KB), then next step's K (4KB)
    bf16x8 vF[4];
    const char* vbase = vb + (size_t)t * 4096;
#pragma unroll
    for (int i = 0; i < 4; ++i) vF[i] = *(const bf16x8*)(vbase + i * 1024 + loff);
    const char* knb = kb + (size_t)(t + 1) * 4096;
#pragma unroll
    for (int i = 0; i < 4; ++i) kn[i] = *(const bf16x8*)(knb + i * 1024 + loff);

    // S^T = K Q^T (exp2 arg): sv[c] = S[t_sub=(c&3)+8*(c>>2)+4*hi5][q=l31]
    f32x16 sv = {};
    __builtin_amdgcn_s_setprio(1);
#pragma unroll
    for (int ds = 0; ds < 4; ++ds) sv = mfma32(kc[ds], qf[ds], sv);
    __builtin_amdgcn_s_setprio(0);

    // softmax + pack: e[0..7] -> pa[0] (keys 0-15), e[8..15] -> pa[1] (16-31)
    float e[16];
#pragma unroll
    for (int c = 0; c < 16; ++c) {
      e[c] = fexp2(sv[c]);
      rs += e[c];
    }
    bf16x8 pa[2];
    unsigned u0 = cvtpk_bf16(e[0], e[1]), v0 = cvtpk_bf16(e[2], e[3]);
    unsigned w0 = cvtpk_bf16(e[4], e[5]), z0 = cvtpk_bf16(e[6], e[7]);
    plswap(u0, w0);
    plswap(v0, z0);
    uint4 pk0 = {u0, v0, w0, z0};
    pa[0] = *(bf16x8*)&pk0;
    unsigned u1 = cvtpk_bf16(e[8], e[9]), v1 = cvtpk_bf16(e[10], e[11]);
    unsigned w1 = cvtpk_bf16(e[12], e[13]), z1 = cvtpk_bf16(e[14], e[15]);
    plswap(u1, w1);
    plswap(v1, z1);
    uint4 pk1 = {u1, v1, w1, z1};
    pa[1] = *(bf16x8*)&pk1;

    // PV: O += P.V  (vF[tl*2+dh]: tl = 16-key slice, dh = d half)
    __builtin_amdgcn_s_setprio(1);
    acc0 = mfma32(pa[0], vF[0], acc0);
    acc1 = mfma32(pa[0], vF[1], acc1);
    acc0 = mfma32(pa[1], vF[2], acc0);
    acc1 = mfma32(pa[1], vF[3], acc1);
    __builtin_amdgcn_s_setprio(0);
  };

  for (int t = 0; t < 64; t += 2) {
    stepf(t, kA, kB);
    stepf(t + 1, kB, kA);  // final prefetch overreads 4KB (harmless, in ws)
  }

  // denominators: lanes l and l^32 both own q=l31 partial sums
  rs += __shfl_xor(rs, 32, 64);

#pragma unroll
  for (int c = 0; c < 16; ++c) {
    int q = (c & 3) + 8 * (c >> 2) + 4 * hi5;
    float dn = __shfl(rs, q, 64);
    float inv = 1.f / dn;
    size_t rowb = (size_t)(q0w + q) * 1024 + h * 64;
    concat[rowb + l31] = f2bf(acc0[c] * inv);
    concat[rowb + 32 + l31] = f2bf(acc1[c] * inv);
  }
}

// ---------------------------------------------------------------------------
extern "C" void kernel_launch(void* const* d_in, const int* in_sizes, int n_in,
                              void* d_out, int out_size, void* d_ws,
                              size_t ws_size, hipStream_t stream) {
  (void)in_sizes; (void)n_in; (void)out_size; (void)ws_size;
  const float* emb = (const float*)d_in[0];
  const float* Wq = (const float*)d_in[1];
  const float* bq = (const float*)d_in[2];
  const float* Wk = (const float*)d_in[3];
  const float* bk = (const float*)d_in[4];
  const float* Wv = (const float*)d_in[5];
  const float* bv = (const float*)d_in[6];
  const float* Wo = (const float*)d_in[7];
  const float* bo = (const float*)d_in[8];

  char* ws = (char*)d_ws;
  u16* emb_bf  = (u16*)(ws + 0);          // 4 MB
  u16* wqkv_t  = (u16*)(ws + 4194304);    // 6 MB
  u16* wo_t    = (u16*)(ws + 10485760);   // 2 MB
  float* bqkv  = (float*)(ws + 12582912); // 12 KB
  u16* qbuf    = (u16*)(ws + 12595200);   // 4 MB
  u16* kpack   = (u16*)(ws + 16789504);   // 4 MB (frag tiles)
  u16* vpack   = (u16*)(ws + 20983808);   // 4 MB (frag tiles)
  u16* concat  = (u16*)(ws + 29372416);   // 4 MB

  convert_kernel<<<3073, 256, 0, stream>>>(emb, Wq, Wk, Wv, bq, bk, bv, Wo,
                                           emb_bf, wqkv_t, wo_t, bqkv);
  gemm_kernel<2, 2, 4, 2, 64, true, true><<<dim3(16, 48), 256, 0, stream>>>(
      emb_bf, wqkv_t, bqkv, qbuf, kpack, vpack, 2048, 3072, 1024);
  attn_kernel<<<256, 256, 0, stream>>>(qbuf, kpack, vpack, concat);
  gemm_kernel<2, 2, 2, 2, 64, false, false><<<dim3(32, 16), 256, 0, stream>>>(
      concat, wo_t, bo, d_out, nullptr, nullptr, 2048, 1024, 1024);
}

// Round 16
// 73.592 us; speedup vs baseline: 1.0108x; 1.0108x over previous
//
#include <hip/hip_runtime.h>
#include <hip/hip_bf16.h>

typedef unsigned short u16;
typedef __attribute__((ext_vector_type(8))) short bf16x8;
typedef __attribute__((ext_vector_type(4))) float f32x4;
typedef __attribute__((ext_vector_type(16))) float f32x16;

#define S_LEN 2048
#define NH 16

__device__ __forceinline__ u16 f2bf(float x) {
  union { float f; unsigned u; } v; v.f = x;
  unsigned r = v.u + 0x7fffu + ((v.u >> 16) & 1u);
  return (u16)(r >> 16);
}

__device__ __forceinline__ unsigned cvtpk_bf16(float lo, float hi) {
  unsigned w;
  asm("v_cvt_pk_bf16_f32 %0, %1, %2" : "=v"(w) : "v"(lo), "v"(hi));
  return w;
}

// swap a's hi 32 lanes with b's lo 32 lanes (both updated)
__device__ __forceinline__ void plswap(unsigned& a, unsigned& b) {
  asm volatile("v_permlane32_swap_b32 %0, %1" : "+v"(a), "+v"(b));
}

__device__ __forceinline__ float fexp2(float x) {
#if __has_builtin(__builtin_amdgcn_exp2f)
  return __builtin_amdgcn_exp2f(x);
#else
  float y;
  asm volatile("v_exp_f32 %0, %1\n\ts_nop 0" : "=v"(y) : "v"(x));
  return y;
#endif
}

__device__ __forceinline__ void async16(const void* g, void* l) {
  __builtin_amdgcn_global_load_lds(
      (const __attribute__((address_space(1))) unsigned int*)g,
      (__attribute__((address_space(3))) unsigned int*)l, 16, 0, 0);
}

__device__ __forceinline__ f32x4 mfma16(bf16x8 a, bf16x8 b, f32x4 c) {
  return __builtin_amdgcn_mfma_f32_16x16x32_bf16(a, b, c, 0, 0, 0);
}
__device__ __forceinline__ f32x16 mfma32(bf16x8 a, bf16x8 b, f32x16 c) {
  return __builtin_amdgcn_mfma_f32_32x32x16_bf16(a, b, c, 0, 0, 0);
}

// scale folded into Wq/bq: 1/sqrt(64) * log2(e) so QK^T output is the exp2 arg
#define QSCALE (0.125f * 1.44269504089f)

// ---------------------------------------------------------------------------
// K1: convert/pack (region-dispatched by blockIdx.x). Unchanged (round 12).
// ---------------------------------------------------------------------------
__global__ __launch_bounds__(256) void convert_kernel(
    const float* __restrict__ emb, const float* __restrict__ Wq,
    const float* __restrict__ Wk, const float* __restrict__ Wv,
    const float* __restrict__ bq, const float* __restrict__ bk,
    const float* __restrict__ bv, const float* __restrict__ Wo,
    u16* __restrict__ emb_bf, u16* __restrict__ wqkv_t,
    u16* __restrict__ wo_t, float* __restrict__ bqkv) {
  __shared__ float lds[64][65];
  const int b = blockIdx.x, tid = threadIdx.x;
  if (b < 2048) {
    int i = b * 1024 + tid * 4;
    float4 v = *(const float4*)(emb + i);
    ushort4 o = {f2bf(v.x), f2bf(v.y), f2bf(v.z), f2bf(v.w)};
    *(ushort4*)(emb_bf + i) = o;
    return;
  }
  if (b < 2816) {
    int tt = b - 2048;
    int kind = tt >> 8;
    int rem = tt & 255;
    int h = rem >> 4, k0 = (rem & 15) << 6;
    const float* W = (kind == 0) ? Wq : ((kind == 1) ? Wk : Wv);
    const float* src = W + ((size_t)h * 1024 + k0) * 64;
#pragma unroll
    for (int rr = 0; rr < 4; ++rr) {
      int k = rr * 16 + (tid >> 4);
      int d4 = (tid & 15) << 2;
      float4 v = *(const float4*)(src + (size_t)k * 64 + d4);
      lds[k][d4] = v.x; lds[k][d4 + 1] = v.y;
      lds[k][d4 + 2] = v.z; lds[k][d4 + 3] = v.w;
    }
    __syncthreads();
    float scale = (kind == 0) ? QSCALE : 1.f;
#pragma unroll
    for (int p = 0; p < 2; ++p) {
      int d = p * 32 + (tid >> 3);
      int kb = (tid & 7) << 3;
      bf16x8 o;
#pragma unroll
      for (int j = 0; j < 8; ++j) o[j] = (short)f2bf(lds[kb + j][d] * scale);
      *(bf16x8*)(wqkv_t + (size_t)(kind * 1024 + h * 64 + d) * 1024 + k0 + kb) = o;
    }
    return;
  }
  if (b < 3072) {
    int tt = b - 2816;
    int k0 = (tt >> 4) << 6, n0 = (tt & 15) << 6;
#pragma unroll
    for (int rr = 0; rr < 4; ++rr) {
      int k = rr * 16 + (tid >> 4);
      int n4 = (tid & 15) << 2;
      float4 v = *(const float4*)(Wo + (size_t)(k0 + k) * 1024 + n0 + n4);
      lds[k][n4] = v.x; lds[k][n4 + 1] = v.y;
      lds[k][n4 + 2] = v.z; lds[k][n4 + 3] = v.w;
    }
    __syncthreads();
#pragma unroll
    for (int p = 0; p < 2; ++p) {
      int nrel = p * 32 + (tid >> 3);
      int kb = (tid & 7) << 3;
      bf16x8 o;
#pragma unroll
      for (int j = 0; j < 8; ++j) o[j] = (short)f2bf(lds[kb + j][nrel]);
      *(bf16x8*)(wo_t + (size_t)(n0 + nrel) * 1024 + k0 + kb) = o;
    }
    return;
  }
  for (int i = tid; i < 3072; i += 256) {
    int kind = i >> 10, hd = i & 1023;
    const float* bb = (kind == 0) ? bq : ((kind == 1) ? bk : bv);
    float v = bb[hd];
    bqkv[i] = (kind == 0) ? v * QSCALE : v;
  }
}

// ---------------------------------------------------------------------------
// GEMM (round-6 proven form: 2-buf, vmcnt(0)+syncthreads). Unchanged.
// SPLIT (GEMM1, BN=64 tiles): Q -> qbuf[2048][1024]; K -> kpack frag tiles;
// V -> vpack frag tiles (lane-linear 1KB tiles).
// ---------------------------------------------------------------------------
template <int WM, int WN, int FM, int FN, int BK, bool OUT_BF16, bool SPLIT>
__global__ __launch_bounds__(WM * WN * 64) void gemm_kernel(
    const u16* __restrict__ A, const u16* __restrict__ BT,
    const float* __restrict__ bias, void* __restrict__ Cout,
    u16* __restrict__ kp, u16* __restrict__ vp, int M, int N, int K) {
  constexpr int BM = WM * FM * 16, BN = WN * FN * 16, T = WM * WN * 64;
  constexpr int RB = BK * 2;
  __shared__ u16 lds[2][(BM + BN) * BK];
  const int tid = threadIdx.x;
  const int lane = tid & 63, wave = tid >> 6;
  const int wr = wave / WN, wc = wave % WN;
  const int m0 = blockIdx.x * BM, n0 = blockIdx.y * BN;
  const int r = lane & 15, g = lane >> 4;
  const f32x4 fzero = {0.f, 0.f, 0.f, 0.f};
  f32x4 acc[FM][FN];
#pragma unroll
  for (int i = 0; i < FM; ++i)
#pragma unroll
    for (int j = 0; j < FN; ++j) acc[i][j] = fzero;

  constexpr int LA = (BM * RB) / (T * 16);
  constexpr int LB = (BN * RB) / (T * 16);

  auto stage = [&](int kt, int buf) {
    int k0 = kt * BK;
#pragma unroll
    for (int i = 0; i < LA; ++i) {
      int flat = i * T * 16 + tid * 16;
      int row = flat / RB, colb = flat % RB;
      async16((const char*)A + ((size_t)(m0 + row) * K + k0) * 2 + colb,
              (char*)lds[buf] + i * T * 16 + wave * 1024);
    }
#pragma unroll
    for (int i = 0; i < LB; ++i) {
      int flat = i * T * 16 + tid * 16;
      int row = flat / RB, colb = flat % RB;
      async16((const char*)BT + ((size_t)(n0 + row) * K + k0) * 2 + colb,
              (char*)lds[buf] + BM * RB + i * T * 16 + wave * 1024);
    }
  };

  stage(0, 0);
  asm volatile("s_waitcnt vmcnt(0)" ::: "memory");
  __syncthreads();

  const int NT = K / BK;
  for (int kt = 0; kt < NT; ++kt) {
    int cur = kt & 1;
    if (kt + 1 < NT) stage(kt + 1, cur ^ 1);
    const u16* Al = lds[cur];
    const u16* Bl = Al + BM * BK;
#pragma unroll
    for (int kk = 0; kk < BK / 32; ++kk) {
      bf16x8 af[FM], bfr[FN];
#pragma unroll
      for (int i = 0; i < FM; ++i)
        af[i] = *(const bf16x8*)&Al[(wr * FM * 16 + i * 16 + r) * BK + kk * 32 + g * 8];
#pragma unroll
      for (int j = 0; j < FN; ++j)
        bfr[j] = *(const bf16x8*)&Bl[(wc * FN * 16 + j * 16 + r) * BK + kk * 32 + g * 8];
#pragma unroll
      for (int i = 0; i < FM; ++i)
#pragma unroll
        for (int j = 0; j < FN; ++j)
          acc[i][j] = mfma16(af[i], bfr[j], acc[i][j]);
    }
    asm volatile("s_waitcnt vmcnt(0)" ::: "memory");
    __syncthreads();
  }

  if constexpr (SPLIT) {
    if (n0 >= 2048) {  // V head -> vpack frag tiles
      int h = (n0 - 2048) >> 6;
      u16* base = vp + (size_t)h * 131072;
#pragma unroll
      for (int i = 0; i < FM; ++i)
#pragma unroll
        for (int j = 0; j < FN; ++j) {
          int d = wc * FN * 16 + j * 16 + r;
          int t0v = m0 + wr * FM * 16 + i * 16 + g * 4;
          float bval = bias[n0 + d];
          int off = (t0v >> 6) * 4096 + ((((t0v >> 4) & 3) * 2 + (d >> 5))) * 512 +
                    ((d & 31) * 2 + ((t0v >> 3) & 1)) * 8 + (t0v & 7);
          ushort4 o = {f2bf(acc[i][j][0] + bval), f2bf(acc[i][j][1] + bval),
                       f2bf(acc[i][j][2] + bval), f2bf(acc[i][j][3] + bval)};
          *(ushort4*)(base + off) = o;
        }
      return;
    }
    if (n0 >= 1024) {  // K head -> kpack frag tiles
      int h = (n0 - 1024) >> 6;
      u16* base = kp + (size_t)h * 131072;
#pragma unroll
      for (int i = 0; i < FM; ++i)
#pragma unroll
        for (int j = 0; j < FN; ++j) {
          int d = wc * FN * 16 + j * 16 + r;
          float bval = bias[n0 + d];
#pragma unroll
          for (int e = 0; e < 4; ++e) {
            int t = m0 + wr * FM * 16 + i * 16 + g * 4 + e;
            int off = (t >> 5) * 2048 + (d >> 4) * 512 +
                      ((t & 31) * 2 + ((d >> 3) & 1)) * 8 + (d & 7);
            base[off] = f2bf(acc[i][j][e] + bval);
          }
        }
      return;
    }
    // Q -> qbuf[2048][1024]
#pragma unroll
    for (int i = 0; i < FM; ++i)
#pragma unroll
      for (int j = 0; j < FN; ++j)
#pragma unroll
        for (int e = 0; e < 4; ++e) {
          int row = m0 + wr * FM * 16 + i * 16 + g * 4 + e;
          int col = n0 + wc * FN * 16 + j * 16 + r;
          ((u16*)Cout)[(size_t)row * 1024 + col] = f2bf(acc[i][j][e] + bias[col]);
        }
    return;
  }

#pragma unroll
  for (int i = 0; i < FM; ++i)
#pragma unroll
    for (int j = 0; j < FN; ++j)
#pragma unroll
      for (int e = 0; e < 4; ++e) {
        int row = m0 + wr * FM * 16 + i * 16 + g * 4 + e;
        int col = n0 + wc * FN * 16 + j * 16 + r;
        float v = acc[i][j][e] + bias[col];
        if constexpr (OUT_BF16)
          ((u16*)Cout)[(size_t)row * N + col] = f2bf(v);
        else
          ((float*)Cout)[(size_t)row * N + col] = v;
      }
}

// ---------------------------------------------------------------------------
// K4: register-resident flash attention (round-8/12 verified datapath) with
// BOTH K and V register-double-buffered: step t computes on kc/vc loaded a
// full step earlier; kn/vn for t+1 are issued at the top -> every load gets
// ~1 full step (>=300cy) of latency cover. NO LDS, NO barriers.
// 256 blocks x 4 waves; wave = 32 q-rows x 2048 keys, one head.
// ---------------------------------------------------------------------------
__global__ __launch_bounds__(256, 1) void attn_kernel(const u16* __restrict__ qbuf,
                                                      const u16* __restrict__ kp,
                                                      const u16* __restrict__ vp,
                                                      u16* __restrict__ concat) {
  const int tid = threadIdx.x, lane = tid & 63, wave = tid >> 6;
  // XCD swizzle: 32 consecutive jobs (2 heads) per XCD
  const int swz = (blockIdx.x & 7) * 32 + (blockIdx.x >> 3);
  const int h = swz >> 4, qg = swz & 15;
  const int q0w = qg * 128 + wave * 32;
  const int l31 = lane & 31, hi5 = lane >> 5;
  const char* kb = (const char*)kp + (size_t)h * 262144;
  const char* vb = (const char*)vp + (size_t)h * 262144;
  const int loff = (l31 * 2 + hi5) * 16;  // lane-linear frag offset (bytes)

  // Q fragments (B-operand): lane holds Q[q=l31][ds*16 + hi5*8 + j]
  bf16x8 qf[4];
#pragma unroll
  for (int ds = 0; ds < 4; ++ds)
    qf[ds] = *(const bf16x8*)&qbuf[(size_t)(q0w + l31) * 1024 + h * 64 + ds * 16 + hi5 * 8];

  f32x16 acc0 = {}, acc1 = {};
  float rs = 0.f;

  bf16x8 kA[8], kB[8], vA[8], vB[8];
#pragma unroll
  for (int i = 0; i < 8; ++i) {
    kA[i] = *(const bf16x8*)(kb + i * 1024 + loff);
    vA[i] = *(const bf16x8*)(vb + i * 1024 + loff);
  }

  auto stepf = [&](int t, bf16x8(&kc)[8], bf16x8(&kn)[8], bf16x8(&vc)[8],
                   bf16x8(&vn)[8]) {
    // prefetch step t+1's K AND V first (full-step latency cover)
    const char* knb = kb + (size_t)(t + 1) * 8192;
    const char* vnb = vb + (size_t)(t + 1) * 8192;
#pragma unroll
    for (int i = 0; i < 8; ++i) {
      kn[i] = *(const bf16x8*)(knb + i * 1024 + loff);
      vn[i] = *(const bf16x8*)(vnb + i * 1024 + loff);
    }

    // S^T = K Q^T (exp2 arg): sv[c] = S[t_sub=(c&3)+8*(c>>2)+4*hi5][q=l31]
    f32x16 sv0 = {}, sv1 = {};
    __builtin_amdgcn_s_setprio(1);
#pragma unroll
    for (int ds = 0; ds < 4; ++ds) {
      sv0 = mfma32(kc[ds], qf[ds], sv0);
      sv1 = mfma32(kc[4 + ds], qf[ds], sv1);
    }
    __builtin_amdgcn_s_setprio(0);

    // softmax + pack to PV A-frags (pa[tsl] covers t-slice of 16)
    bf16x8 pa[4];
#pragma unroll
    for (int s = 0; s < 2; ++s) {
      float e[16];
#pragma unroll
      for (int c = 0; c < 16; ++c) {
        e[c] = fexp2(s == 0 ? sv0[c] : sv1[c]);
        rs += e[c];
      }
      unsigned u0 = cvtpk_bf16(e[0], e[1]), v0 = cvtpk_bf16(e[2], e[3]);
      unsigned w0 = cvtpk_bf16(e[4], e[5]), z0 = cvtpk_bf16(e[6], e[7]);
      plswap(u0, w0);
      plswap(v0, z0);
      uint4 pk0 = {u0, v0, w0, z0};
      pa[2 * s] = *(bf16x8*)&pk0;
      unsigned u1 = cvtpk_bf16(e[8], e[9]), v1 = cvtpk_bf16(e[10], e[11]);
      unsigned w1 = cvtpk_bf16(e[12], e[13]), z1 = cvtpk_bf16(e[14], e[15]);
      plswap(u1, w1);
      plswap(v1, z1);
      uint4 pk1 = {u1, v1, w1, z1};
      pa[2 * s + 1] = *(bf16x8*)&pk1;
    }

    // PV: O += P.V  (acc col = d = l31 + 32*dtl, rows q over regs)
    __builtin_amdgcn_s_setprio(1);
#pragma unroll
    for (int tsl = 0; tsl < 4; ++tsl) {
      acc0 = mfma32(pa[tsl], vc[tsl * 2 + 0], acc0);
      acc1 = mfma32(pa[tsl], vc[tsl * 2 + 1], acc1);
    }
    __builtin_amdgcn_s_setprio(0);
  };

  for (int t = 0; t < 32; t += 2) {
    stepf(t, kA, kB, vA, vB);
    stepf(t + 1, kB, kA, vB, vA);  // final prefetch overreads 16KB (in-ws, harmless)
  }

  // denominators: lanes l and l^32 both own q=l31 partial sums
  rs += __shfl_xor(rs, 32, 64);

#pragma unroll
  for (int c = 0; c < 16; ++c) {
    int q = (c & 3) + 8 * (c >> 2) + 4 * hi5;
    float dn = __shfl(rs, q, 64);
    float inv = 1.f / dn;
    size_t rowb = (size_t)(q0w + q) * 1024 + h * 64;
    concat[rowb + l31] = f2bf(acc0[c] * inv);
    concat[rowb + 32 + l31] = f2bf(acc1[c] * inv);
  }
}

// ---------------------------------------------------------------------------
extern "C" void kernel_launch(void* const* d_in, const int* in_sizes, int n_in,
                              void* d_out, int out_size, void* d_ws,
                              size_t ws_size, hipStream_t stream) {
  (void)in_sizes; (void)n_in; (void)out_size; (void)ws_size;
  const float* emb = (const float*)d_in[0];
  const float* Wq = (const float*)d_in[1];
  const float* bq = (const float*)d_in[2];
  const float* Wk = (const float*)d_in[3];
  const float* bk = (const float*)d_in[4];
  const float* Wv = (const float*)d_in[5];
  const float* bv = (const float*)d_in[6];
  const float* Wo = (const float*)d_in[7];
  const float* bo = (const float*)d_in[8];

  char* ws = (char*)d_ws;
  u16* emb_bf  = (u16*)(ws + 0);          // 4 MB
  u16* wqkv_t  = (u16*)(ws + 4194304);    // 6 MB
  u16* wo_t    = (u16*)(ws + 10485760);   // 2 MB
  float* bqkv  = (float*)(ws + 12582912); // 12 KB
  u16* qbuf    = (u16*)(ws + 12595200);   // 4 MB
  u16* kpack   = (u16*)(ws + 16789504);   // 4 MB (frag tiles)
  u16* vpack   = (u16*)(ws + 20983808);   // 4 MB (frag tiles)
  u16* concat  = (u16*)(ws + 29372416);   // 4 MB

  convert_kernel<<<3073, 256, 0, stream>>>(emb, Wq, Wk, Wv, bq, bk, bv, Wo,
                                           emb_bf, wqkv_t, wo_t, bqkv);
  gemm_kernel<2, 2, 4, 2, 64, true, true><<<dim3(16, 48), 256, 0, stream>>>(
      emb_bf, wqkv_t, bqkv, qbuf, kpack, vpack, 2048, 3072, 1024);
  attn_kernel<<<256, 256, 0, stream>>>(qbuf, kpack, vpack, concat);
  gemm_kernel<2, 2, 2, 2, 64, false, false><<<dim3(32, 16), 256, 0, stream>>>(
      concat, wo_t, bo, d_out, nullptr, nullptr, 2048, 1024, 1024);
}

// Round 17
// 72.161 us; speedup vs baseline: 1.0309x; 1.0198x over previous
//
#include <hip/hip_runtime.h>
#include <hip/hip_bf16.h>

typedef unsigned short u16;
typedef __attribute__((ext_vector_type(8))) short bf16x8;
typedef __attribute__((ext_vector_type(4))) float f32x4;
typedef __attribute__((ext_vector_type(16))) float f32x16;

#define S_LEN 2048
#define NH 16

__device__ __forceinline__ u16 f2bf(float x) {
  union { float f; unsigned u; } v; v.f = x;
  unsigned r = v.u + 0x7fffu + ((v.u >> 16) & 1u);
  return (u16)(r >> 16);
}

__device__ __forceinline__ unsigned cvtpk_bf16(float lo, float hi) {
  unsigned w;
  asm("v_cvt_pk_bf16_f32 %0, %1, %2" : "=v"(w) : "v"(lo), "v"(hi));
  return w;
}

// swap a's hi 32 lanes with b's lo 32 lanes (both updated)
__device__ __forceinline__ void plswap(unsigned& a, unsigned& b) {
  asm volatile("v_permlane32_swap_b32 %0, %1" : "+v"(a), "+v"(b));
}

__device__ __forceinline__ float fexp2(float x) {
#if __has_builtin(__builtin_amdgcn_exp2f)
  return __builtin_amdgcn_exp2f(x);
#else
  float y;
  asm volatile("v_exp_f32 %0, %1\n\ts_nop 0" : "=v"(y) : "v"(x));
  return y;
#endif
}

__device__ __forceinline__ void async16(const void* g, void* l) {
  __builtin_amdgcn_global_load_lds(
      (const __attribute__((address_space(1))) unsigned int*)g,
      (__attribute__((address_space(3))) unsigned int*)l, 16, 0, 0);
}

__device__ __forceinline__ f32x4 mfma16(bf16x8 a, bf16x8 b, f32x4 c) {
  return __builtin_amdgcn_mfma_f32_16x16x32_bf16(a, b, c, 0, 0, 0);
}
__device__ __forceinline__ f32x16 mfma32(bf16x8 a, bf16x8 b, f32x16 c) {
  return __builtin_amdgcn_mfma_f32_32x32x16_bf16(a, b, c, 0, 0, 0);
}

// scale folded into Wq/bq: 1/sqrt(64) * log2(e) so QK^T output is the exp2 arg
#define QSCALE (0.125f * 1.44269504089f)

// ---------------------------------------------------------------------------
// K1: convert/pack (region-dispatched by blockIdx.x). Unchanged (round 12).
// ---------------------------------------------------------------------------
__global__ __launch_bounds__(256) void convert_kernel(
    const float* __restrict__ emb, const float* __restrict__ Wq,
    const float* __restrict__ Wk, const float* __restrict__ Wv,
    const float* __restrict__ bq, const float* __restrict__ bk,
    const float* __restrict__ bv, const float* __restrict__ Wo,
    u16* __restrict__ emb_bf, u16* __restrict__ wqkv_t,
    u16* __restrict__ wo_t, float* __restrict__ bqkv) {
  __shared__ float lds[64][65];
  const int b = blockIdx.x, tid = threadIdx.x;
  if (b < 2048) {
    int i = b * 1024 + tid * 4;
    float4 v = *(const float4*)(emb + i);
    ushort4 o = {f2bf(v.x), f2bf(v.y), f2bf(v.z), f2bf(v.w)};
    *(ushort4*)(emb_bf + i) = o;
    return;
  }
  if (b < 2816) {
    int tt = b - 2048;
    int kind = tt >> 8;
    int rem = tt & 255;
    int h = rem >> 4, k0 = (rem & 15) << 6;
    const float* W = (kind == 0) ? Wq : ((kind == 1) ? Wk : Wv);
    const float* src = W + ((size_t)h * 1024 + k0) * 64;
#pragma unroll
    for (int rr = 0; rr < 4; ++rr) {
      int k = rr * 16 + (tid >> 4);
      int d4 = (tid & 15) << 2;
      float4 v = *(const float4*)(src + (size_t)k * 64 + d4);
      lds[k][d4] = v.x; lds[k][d4 + 1] = v.y;
      lds[k][d4 + 2] = v.z; lds[k][d4 + 3] = v.w;
    }
    __syncthreads();
    float scale = (kind == 0) ? QSCALE : 1.f;
#pragma unroll
    for (int p = 0; p < 2; ++p) {
      int d = p * 32 + (tid >> 3);
      int kb = (tid & 7) << 3;
      bf16x8 o;
#pragma unroll
      for (int j = 0; j < 8; ++j) o[j] = (short)f2bf(lds[kb + j][d] * scale);
      *(bf16x8*)(wqkv_t + (size_t)(kind * 1024 + h * 64 + d) * 1024 + k0 + kb) = o;
    }
    return;
  }
  if (b < 3072) {
    int tt = b - 2816;
    int k0 = (tt >> 4) << 6, n0 = (tt & 15) << 6;
#pragma unroll
    for (int rr = 0; rr < 4; ++rr) {
      int k = rr * 16 + (tid >> 4);
      int n4 = (tid & 15) << 2;
      float4 v = *(const float4*)(Wo + (size_t)(k0 + k) * 1024 + n0 + n4);
      lds[k][n4] = v.x; lds[k][n4 + 1] = v.y;
      lds[k][n4 + 2] = v.z; lds[k][n4 + 3] = v.w;
    }
    __syncthreads();
#pragma unroll
    for (int p = 0; p < 2; ++p) {
      int nrel = p * 32 + (tid >> 3);
      int kb = (tid & 7) << 3;
      bf16x8 o;
#pragma unroll
      for (int j = 0; j < 8; ++j) o[j] = (short)f2bf(lds[kb + j][nrel]);
      *(bf16x8*)(wo_t + (size_t)(n0 + nrel) * 1024 + k0 + kb) = o;
    }
    return;
  }
  for (int i = tid; i < 3072; i += 256) {
    int kind = i >> 10, hd = i & 1023;
    const float* bb = (kind == 0) ? bq : ((kind == 1) ? bk : bv);
    float v = bb[hd];
    bqkv[i] = (kind == 0) ? v * QSCALE : v;
  }
}

// ---------------------------------------------------------------------------
// GEMM (2-buf, vmcnt(0)+syncthreads). SPLIT epilogue generalized to any BN
// (head index derived per column — numerically verified in round 13).
// Q -> qbuf[2048][1024]; K -> kpack frag tiles; V -> vpack frag tiles.
// ---------------------------------------------------------------------------
template <int WM, int WN, int FM, int FN, int BK, bool OUT_BF16, bool SPLIT>
__global__ __launch_bounds__(WM * WN * 64) void gemm_kernel(
    const u16* __restrict__ A, const u16* __restrict__ BT,
    const float* __restrict__ bias, void* __restrict__ Cout,
    u16* __restrict__ kp, u16* __restrict__ vp, int M, int N, int K) {
  constexpr int BM = WM * FM * 16, BN = WN * FN * 16, T = WM * WN * 64;
  constexpr int RB = BK * 2;
  __shared__ u16 lds[2][(BM + BN) * BK];
  const int tid = threadIdx.x;
  const int lane = tid & 63, wave = tid >> 6;
  const int wr = wave / WN, wc = wave % WN;
  const int m0 = blockIdx.x * BM, n0 = blockIdx.y * BN;
  const int r = lane & 15, g = lane >> 4;
  const f32x4 fzero = {0.f, 0.f, 0.f, 0.f};
  f32x4 acc[FM][FN];
#pragma unroll
  for (int i = 0; i < FM; ++i)
#pragma unroll
    for (int j = 0; j < FN; ++j) acc[i][j] = fzero;

  constexpr int LA = (BM * RB) / (T * 16);
  constexpr int LB = (BN * RB) / (T * 16);

  auto stage = [&](int kt, int buf) {
    int k0 = kt * BK;
#pragma unroll
    for (int i = 0; i < LA; ++i) {
      int flat = i * T * 16 + tid * 16;
      int row = flat / RB, colb = flat % RB;
      async16((const char*)A + ((size_t)(m0 + row) * K + k0) * 2 + colb,
              (char*)lds[buf] + i * T * 16 + wave * 1024);
    }
#pragma unroll
    for (int i = 0; i < LB; ++i) {
      int flat = i * T * 16 + tid * 16;
      int row = flat / RB, colb = flat % RB;
      async16((const char*)BT + ((size_t)(n0 + row) * K + k0) * 2 + colb,
              (char*)lds[buf] + BM * RB + i * T * 16 + wave * 1024);
    }
  };

  stage(0, 0);
  asm volatile("s_waitcnt vmcnt(0)" ::: "memory");
  __syncthreads();

  const int NT = K / BK;
  for (int kt = 0; kt < NT; ++kt) {
    int cur = kt & 1;
    if (kt + 1 < NT) stage(kt + 1, cur ^ 1);
    const u16* Al = lds[cur];
    const u16* Bl = Al + BM * BK;
#pragma unroll
    for (int kk = 0; kk < BK / 32; ++kk) {
      bf16x8 af[FM], bfr[FN];
#pragma unroll
      for (int i = 0; i < FM; ++i)
        af[i] = *(const bf16x8*)&Al[(wr * FM * 16 + i * 16 + r) * BK + kk * 32 + g * 8];
#pragma unroll
      for (int j = 0; j < FN; ++j)
        bfr[j] = *(const bf16x8*)&Bl[(wc * FN * 16 + j * 16 + r) * BK + kk * 32 + g * 8];
#pragma unroll
      for (int i = 0; i < FM; ++i)
#pragma unroll
        for (int j = 0; j < FN; ++j)
          acc[i][j] = mfma16(af[i], bfr[j], acc[i][j]);
    }
    asm volatile("s_waitcnt vmcnt(0)" ::: "memory");
    __syncthreads();
  }

  if constexpr (SPLIT) {
    if (n0 >= 2048) {  // V heads -> vpack frag tiles
#pragma unroll
      for (int i = 0; i < FM; ++i)
#pragma unroll
        for (int j = 0; j < FN; ++j) {
          int d = wc * FN * 16 + j * 16 + r;      // 0..BN-1
          int hd = n0 - 2048 + d;
          int h = hd >> 6, dd = hd & 63;
          u16* base = vp + (size_t)h * 131072;
          int t0v = m0 + wr * FM * 16 + i * 16 + g * 4;
          float bval = bias[n0 + d];
          int off = (t0v >> 6) * 4096 + ((((t0v >> 4) & 3) * 2 + (dd >> 5))) * 512 +
                    ((dd & 31) * 2 + ((t0v >> 3) & 1)) * 8 + (t0v & 7);
          ushort4 o = {f2bf(acc[i][j][0] + bval), f2bf(acc[i][j][1] + bval),
                       f2bf(acc[i][j][2] + bval), f2bf(acc[i][j][3] + bval)};
          *(ushort4*)(base + off) = o;
        }
      return;
    }
    if (n0 >= 1024) {  // K heads -> kpack frag tiles
#pragma unroll
      for (int i = 0; i < FM; ++i)
#pragma unroll
        for (int j = 0; j < FN; ++j) {
          int d = wc * FN * 16 + j * 16 + r;
          int hd = n0 - 1024 + d;
          int h = hd >> 6, dd = hd & 63;
          u16* base = kp + (size_t)h * 131072;
          float bval = bias[n0 + d];
#pragma unroll
          for (int e = 0; e < 4; ++e) {
            int t = m0 + wr * FM * 16 + i * 16 + g * 4 + e;
            int off = (t >> 5) * 2048 + (dd >> 4) * 512 +
                      ((t & 31) * 2 + ((dd >> 3) & 1)) * 8 + (dd & 7);
            base[off] = f2bf(acc[i][j][e] + bval);
          }
        }
      return;
    }
    // Q -> qbuf[2048][1024]
#pragma unroll
    for (int i = 0; i < FM; ++i)
#pragma unroll
      for (int j = 0; j < FN; ++j)
#pragma unroll
        for (int e = 0; e < 4; ++e) {
          int row = m0 + wr * FM * 16 + i * 16 + g * 4 + e;
          int col = n0 + wc * FN * 16 + j * 16 + r;
          ((u16*)Cout)[(size_t)row * 1024 + col] = f2bf(acc[i][j][e] + bias[col]);
        }
    return;
  }

#pragma unroll
  for (int i = 0; i < FM; ++i)
#pragma unroll
    for (int j = 0; j < FN; ++j)
#pragma unroll
      for (int e = 0; e < 4; ++e) {
        int row = m0 + wr * FM * 16 + i * 16 + g * 4 + e;
        int col = n0 + wc * FN * 16 + j * 16 + r;
        float v = acc[i][j][e] + bias[col];
        if constexpr (OUT_BF16)
          ((u16*)Cout)[(size_t)row * N + col] = f2bf(v);
        else
          ((float*)Cout)[(size_t)row * N + col] = v;
      }
}

// ---------------------------------------------------------------------------
// K4: register-resident flash attention (round-8/12 verified, byte-identical).
// NO LDS, NO barriers. 256 blocks x 4 waves; wave = 32 q-rows x 2048 keys.
// ---------------------------------------------------------------------------
__global__ __launch_bounds__(256, 1) void attn_kernel(const u16* __restrict__ qbuf,
                                                      const u16* __restrict__ kp,
                                                      const u16* __restrict__ vp,
                                                      u16* __restrict__ concat) {
  const int tid = threadIdx.x, lane = tid & 63, wave = tid >> 6;
  // XCD swizzle: 32 consecutive jobs (2 heads) per XCD
  const int swz = (blockIdx.x & 7) * 32 + (blockIdx.x >> 3);
  const int h = swz >> 4, qg = swz & 15;
  const int q0w = qg * 128 + wave * 32;
  const int l31 = lane & 31, hi5 = lane >> 5;
  const char* kb = (const char*)kp + (size_t)h * 262144;
  const char* vb = (const char*)vp + (size_t)h * 262144;
  const int loff = (l31 * 2 + hi5) * 16;  // lane-linear frag offset (bytes)

  // Q fragments (B-operand): lane holds Q[q=l31][ds*16 + hi5*8 + j]
  bf16x8 qf[4];
#pragma unroll
  for (int ds = 0; ds < 4; ++ds)
    qf[ds] = *(const bf16x8*)&qbuf[(size_t)(q0w + l31) * 1024 + h * 64 + ds * 16 + hi5 * 8];

  f32x16 acc0 = {}, acc1 = {};
  float rs = 0.f;

  bf16x8 kA[8], kB[8];
#pragma unroll
  for (int i = 0; i < 8; ++i) kA[i] = *(const bf16x8*)(kb + i * 1024 + loff);

  auto stepf = [&](int t, bf16x8(&kc)[8], bf16x8(&kn)[8]) {
    // V frags for this step, then next step's K (V returns first)
    bf16x8 vF[8];
    const char* vbase = vb + (size_t)t * 8192;
#pragma unroll
    for (int i = 0; i < 8; ++i) vF[i] = *(const bf16x8*)(vbase + i * 1024 + loff);
    const char* knb = kb + (size_t)(t + 1) * 8192;
#pragma unroll
    for (int i = 0; i < 8; ++i) kn[i] = *(const bf16x8*)(knb + i * 1024 + loff);

    // S^T = K Q^T (exp2 arg): sv[c] = S[t_sub=(c&3)+8*(c>>2)+4*hi5][q=l31]
    f32x16 sv0 = {}, sv1 = {};
    __builtin_amdgcn_s_setprio(1);
#pragma unroll
    for (int ds = 0; ds < 4; ++ds) {
      sv0 = mfma32(kc[ds], qf[ds], sv0);
      sv1 = mfma32(kc[4 + ds], qf[ds], sv1);
    }
    __builtin_amdgcn_s_setprio(0);

    // softmax + pack to PV A-frags (pa[tsl] covers t-slice of 16)
    bf16x8 pa[4];
#pragma unroll
    for (int s = 0; s < 2; ++s) {
      float e[16];
#pragma unroll
      for (int c = 0; c < 16; ++c) {
        e[c] = fexp2(s == 0 ? sv0[c] : sv1[c]);
        rs += e[c];
      }
      unsigned u0 = cvtpk_bf16(e[0], e[1]), v0 = cvtpk_bf16(e[2], e[3]);
      unsigned w0 = cvtpk_bf16(e[4], e[5]), z0 = cvtpk_bf16(e[6], e[7]);
      plswap(u0, w0);
      plswap(v0, z0);
      uint4 pk0 = {u0, v0, w0, z0};
      pa[2 * s] = *(bf16x8*)&pk0;
      unsigned u1 = cvtpk_bf16(e[8], e[9]), v1 = cvtpk_bf16(e[10], e[11]);
      unsigned w1 = cvtpk_bf16(e[12], e[13]), z1 = cvtpk_bf16(e[14], e[15]);
      plswap(u1, w1);
      plswap(v1, z1);
      uint4 pk1 = {u1, v1, w1, z1};
      pa[2 * s + 1] = *(bf16x8*)&pk1;
    }

    // PV: O += P.V  (acc col = d = l31 + 32*dtl, rows q over regs)
    __builtin_amdgcn_s_setprio(1);
#pragma unroll
    for (int tsl = 0; tsl < 4; ++tsl) {
      acc0 = mfma32(pa[tsl], vF[tsl * 2 + 0], acc0);
      acc1 = mfma32(pa[tsl], vF[tsl * 2 + 1], acc1);
    }
    __builtin_amdgcn_s_setprio(0);
  };

  for (int t = 0; t < 32; t += 2) {
    stepf(t, kA, kB);
    stepf(t + 1, kB, kA);  // final prefetch overreads 16KB (harmless, in ws)
  }

  // denominators: lanes l and l^32 both own q=l31 partial sums
  rs += __shfl_xor(rs, 32, 64);

#pragma unroll
  for (int c = 0; c < 16; ++c) {
    int q = (c & 3) + 8 * (c >> 2) + 4 * hi5;
    float dn = __shfl(rs, q, 64);
    float inv = 1.f / dn;
    size_t rowb = (size_t)(q0w + q) * 1024 + h * 64;
    concat[rowb + l31] = f2bf(acc0[c] * inv);
    concat[rowb + 32 + l31] = f2bf(acc1[c] * inv);
  }
}

// ---------------------------------------------------------------------------
extern "C" void kernel_launch(void* const* d_in, const int* in_sizes, int n_in,
                              void* d_out, int out_size, void* d_ws,
                              size_t ws_size, hipStream_t stream) {
  (void)in_sizes; (void)n_in; (void)out_size; (void)ws_size;
  const float* emb = (const float*)d_in[0];
  const float* Wq = (const float*)d_in[1];
  const float* bq = (const float*)d_in[2];
  const float* Wk = (const float*)d_in[3];
  const float* bk = (const float*)d_in[4];
  const float* Wv = (const float*)d_in[5];
  const float* bv = (const float*)d_in[6];
  const float* Wo = (const float*)d_in[7];
  const float* bo = (const float*)d_in[8];

  char* ws = (char*)d_ws;
  u16* emb_bf  = (u16*)(ws + 0);          // 4 MB
  u16* wqkv_t  = (u16*)(ws + 4194304);    // 6 MB
  u16* wo_t    = (u16*)(ws + 10485760);   // 2 MB
  float* bqkv  = (float*)(ws + 12582912); // 12 KB
  u16* qbuf    = (u16*)(ws + 12595200);   // 4 MB
  u16* kpack   = (u16*)(ws + 16789504);   // 4 MB (frag tiles)
  u16* vpack   = (u16*)(ws + 20983808);   // 4 MB (frag tiles)
  u16* concat  = (u16*)(ws + 29372416);   // 4 MB

  convert_kernel<<<3073, 256, 0, stream>>>(emb, Wq, Wk, Wv, bq, bk, bv, Wo,
                                           emb_bf, wqkv_t, wo_t, bqkv);
  gemm_kernel<2, 2, 4, 4, 32, true, true><<<dim3(16, 24), 256, 0, stream>>>(
      emb_bf, wqkv_t, bqkv, qbuf, kpack, vpack, 2048, 3072, 1024);
  attn_kernel<<<256, 256, 0, stream>>>(qbuf, kpack, vpack, concat);
  gemm_kernel<2, 2, 2, 2, 64, false, false><<<dim3(32, 16), 256, 0, stream>>>(
      concat, wo_t, bo, d_out, nullptr, nullptr, 2048, 1024, 1024);
}